// Round 13
// baseline (121.266 us; speedup 1.0000x reference)
//
#include <hip/hip_runtime.h>
#include <hip/hip_bf16.h>

// GCN block: 3 x { t = relu(h @ W^T); h' = A_coo @ t (per sample) }
// B=8, N=10000, D=64, E=160000.
//
// Round 13:
//  - Dual-stream spmm gather: each wave walks its row's edge list as two
//    concurrent halves (2 independent VMEM dep-chains, unroll 4 -> ~8 loads
//    in flight). Round-12 analysis: spmm ~23us vs ~5-10us BW floor ->
//    latency-bound with ~7KB/CU in flight.
//  - Col-tile CSR (T=4) dropped: measured neutral for spmm, costs build.
//    Plain row CSR; single LDS scan kernel (round-6 proven); zero+cvt_w
//    merged. 8 launches total (was 11).
//  - gemm_mfma / fused MFMA structure unchanged from round 12.

#define GCN_B 8
#define GCN_N 10000
#define GCN_D 64
#define GCN_E 160000
#define GCN_BN (GCN_B * GCN_N)

typedef __attribute__((ext_vector_type(8))) short short8v;
typedef __attribute__((ext_vector_type(4))) float float4v;

static __device__ __forceinline__ unsigned short f2bf(float f) {
    __hip_bfloat16 h = __float2bfloat16(f);
    return *reinterpret_cast<unsigned short*>(&h);
}

// ---------------- zero cnt + W f32 -> bf16 (one kernel) ----------------
__global__ __launch_bounds__(256) void zero_cvt_kernel(
    int* __restrict__ cnt,
    const float* __restrict__ W0, const float* __restrict__ W1,
    const float* __restrict__ W2, unsigned short* __restrict__ Wb)
{
    int i = blockIdx.x * 256 + threadIdx.x;   // grid 48 -> 12288
    if (i < GCN_N) cnt[i] = 0;
    if (i < 4096)        Wb[i] = f2bf(W0[i]);
    else if (i < 8192)   Wb[i] = f2bf(W1[i - 4096]);
    else if (i < 12288)  Wb[i] = f2bf(W2[i - 8192]);
}

__global__ __launch_bounds__(256) void hist_kernel(
    const int* __restrict__ rows, int* __restrict__ cnt, int E)
{
    int e = blockIdx.x * 256 + threadIdx.x;
    if (e < E) atomicAdd(&cnt[rows[e]], 1);
}

// Single-block LDS scan over 10000 counters (round-6 proven).
__global__ __launch_bounds__(256) void scan_kernel(
    const int* __restrict__ cnt, int* __restrict__ rp, int* __restrict__ cur)
{
    __shared__ int sc[GCN_N];      // 40 KB
    __shared__ int part[256];
    const int tid = threadIdx.x;

    for (int i = tid; i < GCN_N; i += 256) sc[i] = cnt[i];
    __syncthreads();

    const int per = (GCN_N + 255) / 256;   // 40
    const int base = tid * per;
    int s = 0;
    for (int i = 0; i < per; ++i) {
        int idx = base + i;
        if (idx < GCN_N) s += sc[idx];
    }
    part[tid] = s;
    __syncthreads();
    for (int off = 1; off < 256; off <<= 1) {
        int add = (tid >= off) ? part[tid - off] : 0;
        __syncthreads();
        part[tid] += add;
        __syncthreads();
    }
    int run = part[tid] - s;
    for (int i = 0; i < per; ++i) {
        int idx = base + i;
        if (idx < GCN_N) {
            int c = sc[idx];
            sc[idx] = run;
            run += c;
        }
    }
    __syncthreads();
    for (int i = tid; i < GCN_N; i += 256) {
        int v = sc[i];
        rp[i] = v;
        cur[i] = v;
    }
    if (tid == 0) rp[GCN_N] = GCN_E;
}

__global__ __launch_bounds__(256) void scatter_kernel(
    const float* __restrict__ vals, const int* __restrict__ rows,
    const int* __restrict__ cols, int* __restrict__ cur,
    float* __restrict__ pval, int* __restrict__ pcol, int E)
{
    int e = blockIdx.x * 256 + threadIdx.x;
    if (e >= E) return;
    int pos = atomicAdd(&cur[rows[e]], 1);
    pval[pos] = vals[e];
    pcol[pos] = cols[e];
}

// ---------------- layer-1 GEMM + ReLU via MFMA (f32 x input) ----------------
__global__ __launch_bounds__(256) void gemm_mfma(
    const float* __restrict__ hin,           // f32 [b][n][64]
    const unsigned short* __restrict__ Wb,   // [64][64] bf16
    unsigned short* __restrict__ t)          // bf16 [n][512] flat
{
    __shared__ unsigned short hs[64 * 72];
    __shared__ unsigned short wsm[64 * 72];

    const int tid = threadIdx.x;
    const int g0 = blockIdx.x * 64;

    {   // stage W
        const int row = tid >> 2, seg = tid & 3;
        const uint4* src = reinterpret_cast<const uint4*>(Wb + row * 64 + seg * 16);
        uint4 a = src[0], b = src[1];
        *reinterpret_cast<uint4*>(&wsm[row * 72 + seg * 16])     = a;
        *reinterpret_cast<uint4*>(&wsm[row * 72 + seg * 16 + 8]) = b;
    }
    {   // stage h tile: f32 permuted read, convert to bf16
        const int row = tid >> 2, seg = tid & 3;
        const int g = g0 + row;
        const int n = g >> 3, b = g & 7;
        const float4* src = reinterpret_cast<const float4*>(
            hin + ((size_t)b * GCN_N + n) * 64 + seg * 16);
        float4 v0 = src[0], v1 = src[1], v2 = src[2], v3 = src[3];
        float vv[16] = {v0.x, v0.y, v0.z, v0.w, v1.x, v1.y, v1.z, v1.w,
                        v2.x, v2.y, v2.z, v2.w, v3.x, v3.y, v3.z, v3.w};
        unsigned int p[8];
#pragma unroll
        for (int j = 0; j < 8; ++j)
            p[j] = (unsigned int)f2bf(vv[2 * j]) |
                   ((unsigned int)f2bf(vv[2 * j + 1]) << 16);
        *reinterpret_cast<uint4*>(&hs[row * 72 + seg * 16]) =
            make_uint4(p[0], p[1], p[2], p[3]);
        *reinterpret_cast<uint4*>(&hs[row * 72 + seg * 16 + 8]) =
            make_uint4(p[4], p[5], p[6], p[7]);
    }
    __syncthreads();

    const int w = tid >> 6;
    const int l = tid & 63;
    const int rbase = w * 16;
    const int arow = rbase + (l & 15);
    const int koff = (l >> 4) * 8;

    float4v acc[4];
#pragma unroll
    for (int nt = 0; nt < 4; ++nt) acc[nt] = (float4v){0.f, 0.f, 0.f, 0.f};

#pragma unroll
    for (int kc = 0; kc < 2; ++kc) {
        short8v afrag = *reinterpret_cast<const short8v*>(
            &hs[arow * 72 + kc * 32 + koff]);
#pragma unroll
        for (int nt = 0; nt < 4; ++nt) {
            short8v bfrag = *reinterpret_cast<const short8v*>(
                &wsm[(nt * 16 + (l & 15)) * 72 + kc * 32 + koff]);
            acc[nt] = __builtin_amdgcn_mfma_f32_16x16x32_bf16(
                afrag, bfrag, acc[nt], 0, 0, 0);
        }
    }

    const int crow = rbase + (l >> 4) * 4;
    const int col = l & 15;
#pragma unroll
    for (int nt = 0; nt < 4; ++nt)
#pragma unroll
        for (int r4 = 0; r4 < 4; ++r4)
            t[(size_t)(g0 + crow + r4) * 64 + nt * 16 + col] =
                f2bf(fmaxf(acc[nt][r4], 0.0f));
}

// dual-stream gather: accumulate row r's edges into a[8] (f32).
static __device__ __forceinline__ void gather_row(
    const uint4* __restrict__ t4_in, const float* __restrict__ pval,
    const int* __restrict__ pcol, int beg, int end, int lane, float* a)
{
    const int len = end - beg;
    const int half = len >> 1;
    const int mid = beg + half;

#pragma unroll 4
    for (int k = 0; k < half; ++k) {
        const float vA = pval[beg + k];
        const int   cA = pcol[beg + k];
        const float vB = pval[mid + k];
        const int   cB = pcol[mid + k];
        uint4 uA = t4_in[(size_t)cA * 64 + lane];
        uint4 uB = t4_in[(size_t)cB * 64 + lane];
        a[0] += vA * __uint_as_float(uA.x << 16);
        a[1] += vA * __uint_as_float(uA.x & 0xffff0000u);
        a[2] += vA * __uint_as_float(uA.y << 16);
        a[3] += vA * __uint_as_float(uA.y & 0xffff0000u);
        a[4] += vA * __uint_as_float(uA.z << 16);
        a[5] += vA * __uint_as_float(uA.z & 0xffff0000u);
        a[6] += vA * __uint_as_float(uA.w << 16);
        a[7] += vA * __uint_as_float(uA.w & 0xffff0000u);
        a[0] += vB * __uint_as_float(uB.x << 16);
        a[1] += vB * __uint_as_float(uB.x & 0xffff0000u);
        a[2] += vB * __uint_as_float(uB.y << 16);
        a[3] += vB * __uint_as_float(uB.y & 0xffff0000u);
        a[4] += vB * __uint_as_float(uB.z << 16);
        a[5] += vB * __uint_as_float(uB.z & 0xffff0000u);
        a[6] += vB * __uint_as_float(uB.w << 16);
        a[7] += vB * __uint_as_float(uB.w & 0xffff0000u);
    }
    if (len & 1) {
        const float v = pval[end - 1];
        const int   c = pcol[end - 1];
        uint4 u = t4_in[(size_t)c * 64 + lane];
        a[0] += v * __uint_as_float(u.x << 16);
        a[1] += v * __uint_as_float(u.x & 0xffff0000u);
        a[2] += v * __uint_as_float(u.y << 16);
        a[3] += v * __uint_as_float(u.y & 0xffff0000u);
        a[4] += v * __uint_as_float(u.z << 16);
        a[5] += v * __uint_as_float(u.z & 0xffff0000u);
        a[6] += v * __uint_as_float(u.w << 16);
        a[7] += v * __uint_as_float(u.w & 0xffff0000u);
    }
}

// ---------------- fused SpMM -> GEMM + ReLU ----------------
__global__ __launch_bounds__(512) void spmm_gemm_fused(
    const uint4* __restrict__ t4_in,
    const float* __restrict__ pval,
    const int* __restrict__ pcol,
    const int* __restrict__ rp,              // [N+1]
    const unsigned short* __restrict__ Wb,
    unsigned short* __restrict__ t_out)
{
    __shared__ unsigned short hs[64 * 72];
    __shared__ unsigned short wsm[64 * 72];

    const int tid = threadIdx.x;
    const int g0 = blockIdx.x * 64;

    {   // stage W: 512 threads x one uint4
        const int row = tid >> 3, seg = tid & 7;
        uint4 v = *reinterpret_cast<const uint4*>(Wb + row * 64 + seg * 8);
        *reinterpret_cast<uint4*>(&wsm[row * 72 + seg * 8]) = v;
    }

    const int w = tid >> 6;
    const int lane = tid & 63;
    const int r = blockIdx.x * 8 + w;

    float a[8];
#pragma unroll
    for (int i = 0; i < 8; ++i) a[i] = 0.f;
    gather_row(t4_in, pval, pcol, rp[r], rp[r + 1], lane, a);

    {   // pack h'[r] bf16 into hs
        unsigned int p[4];
#pragma unroll
        for (int k = 0; k < 4; ++k)
            p[k] = (unsigned int)f2bf(a[2 * k]) |
                   ((unsigned int)f2bf(a[2 * k + 1]) << 16);
        *reinterpret_cast<uint4*>(
            &hs[(w * 8 + (lane >> 3)) * 72 + (lane & 7) * 8]) =
            make_uint4(p[0], p[1], p[2], p[3]);
    }
    __syncthreads();

    const int q = w >> 1, pr = w & 1;
    const int arow = q * 16 + (lane & 15);
    const int koff = (lane >> 4) * 8;

    float4v acc[2];
    acc[0] = (float4v){0.f, 0.f, 0.f, 0.f};
    acc[1] = (float4v){0.f, 0.f, 0.f, 0.f};

#pragma unroll
    for (int kc = 0; kc < 2; ++kc) {
        short8v afrag = *reinterpret_cast<const short8v*>(
            &hs[arow * 72 + kc * 32 + koff]);
#pragma unroll
        for (int nt2 = 0; nt2 < 2; ++nt2) {
            const int nt = pr * 2 + nt2;
            short8v bfrag = *reinterpret_cast<const short8v*>(
                &wsm[(nt * 16 + (lane & 15)) * 72 + kc * 32 + koff]);
            acc[nt2] = __builtin_amdgcn_mfma_f32_16x16x32_bf16(
                afrag, bfrag, acc[nt2], 0, 0, 0);
        }
    }

    const int crow = q * 16 + (lane >> 4) * 4;
    const int col = lane & 15;
#pragma unroll
    for (int nt2 = 0; nt2 < 2; ++nt2) {
        const int nt = pr * 2 + nt2;
#pragma unroll
        for (int r4 = 0; r4 < 4; ++r4)
            t_out[(size_t)(g0 + crow + r4) * 64 + nt * 16 + col] =
                f2bf(fmaxf(acc[nt2][r4], 0.0f));
    }
}

// ---------------- final standalone SpMM (f32 [b][n][64] out) ----------------
__global__ __launch_bounds__(256) void spmm_final(
    const uint4* __restrict__ t4,
    const float* __restrict__ pval,
    const int* __restrict__ pcol,
    const int* __restrict__ rp,
    float* __restrict__ outf)
{
    const int r = (blockIdx.x * 256 + threadIdx.x) >> 6;
    const int lane = threadIdx.x & 63;
    if (r >= GCN_N) return;

    float a[8];
#pragma unroll
    for (int i = 0; i < 8; ++i) a[i] = 0.f;
    gather_row(t4, pval, pcol, rp[r], rp[r + 1], lane, a);

    const int b = lane >> 3;
    const int d0 = (lane & 7) * 8;
    float* op = outf + ((size_t)b * GCN_N + r) * 64 + d0;
    *reinterpret_cast<float4*>(op)     = make_float4(a[0], a[1], a[2], a[3]);
    *reinterpret_cast<float4*>(op + 4) = make_float4(a[4], a[5], a[6], a[7]);
}

extern "C" void kernel_launch(void* const* d_in, const int* in_sizes, int n_in,
                              void* d_out, int out_size, void* d_ws, size_t ws_size,
                              hipStream_t stream) {
    const float* x    = (const float*)d_in[0];
    const float* W0   = (const float*)d_in[1];
    const float* W1   = (const float*)d_in[2];
    const float* W2   = (const float*)d_in[3];
    const float* vals = (const float*)d_in[4];
    const int*   rows = (const int*)d_in[5];
    const int*   cols = (const int*)d_in[6];

    const size_t t_bytes = (size_t)GCN_BN * GCN_D * 2;   // bf16: 10,240,000

    char* ws = (char*)d_ws;
    unsigned short* tA = (unsigned short*)ws;
    size_t off = (t_bytes + 255) / 256 * 256;
    int*   rp   = (int*)(ws + off); off += ((GCN_N + 1) * 4 + 255) / 256 * 256;
    int*   cur  = (int*)(ws + off); off += (GCN_N * 4 + 255) / 256 * 256;
    int*   cnt  = (int*)(ws + off); off += (GCN_N * 4 + 255) / 256 * 256;
    float* pval = (float*)(ws + off); off += GCN_E * 4;
    int*   pcol = (int*)(ws + off); off += GCN_E * 4;
    unsigned short* Wb = (unsigned short*)(ws + off); off += 3 * 4096 * 2;

    unsigned short* t2 = (unsigned short*)d_out;   // bf16 scratch in d_out
    float* outf = (float*)d_out;                   // final f32 output

    const int gemm_grid = GCN_BN / 64;                // 1250
    const int edge_grid = (GCN_E + 255) / 256;        // 625
    const int spmm_grid = (GCN_N * 64 + 255) / 256;   // 2500

    // Build row-keyed CSR once; reused by all 3 layers.
    zero_cvt_kernel<<<48, 256, 0, stream>>>(cnt, W0, W1, W2, Wb);
    hist_kernel<<<edge_grid, 256, 0, stream>>>(rows, cnt, GCN_E);
    scan_kernel<<<1, 256, 0, stream>>>(cnt, rp, cur);
    scatter_kernel<<<edge_grid, 256, 0, stream>>>(vals, rows, cols, cur, pval, pcol, GCN_E);

    // layer 1: x -> t1 (tA)
    gemm_mfma<<<gemm_grid, 256, 0, stream>>>(x, Wb, tA);
    // layer 1 spmm + layer 2 gemm: tA -> t2 (d_out, bf16)
    spmm_gemm_fused<<<gemm_grid, 512, 0, stream>>>(
        (const uint4*)tA, pval, pcol, rp, Wb + 4096, t2);
    // layer 2 spmm + layer 3 gemm: t2 -> t3 (tA)
    spmm_gemm_fused<<<gemm_grid, 512, 0, stream>>>(
        (const uint4*)t2, pval, pcol, rp, Wb + 8192, tA);
    // layer 3 spmm: tA -> d_out f32 [b][n][64] (full overwrite)
    spmm_final<<<spmm_grid, 256, 0, stream>>>((const uint4*)tA, pval, pcol, rp, outf);
}